// Round 3
// baseline (246.206 us; speedup 1.0000x reference)
//
#include <hip/hip_runtime.h>
#include <hip/hip_bf16.h>
#include <math.h>

#define BB 1024
#define DD 64
#define HH 128

typedef __bf16 bf16x8 __attribute__((ext_vector_type(8)));
typedef float floatx4 __attribute__((ext_vector_type(4)));

__device__ __forceinline__ unsigned short f2bf(float v) {
    union { float f; unsigned u; } a; a.f = v;
    unsigned r = a.u + 0x7fffu + ((a.u >> 16) & 1u);
    return (unsigned short)(r >> 16);
}

// async global -> LDS, 16B per lane. lds base must be wave-uniform; HW adds lane*16.
__device__ __forceinline__ void async_cp16(const float* g, float* lds_wave_base) {
    __builtin_amdgcn_global_load_lds(
        (const __attribute__((address_space(1))) unsigned int*)g,
        (__attribute__((address_space(3))) unsigned int*)lds_wave_base,
        16, 0, 0);
}

// ---------------------------------------------------------------------------
// Prep: c1[i,h] = x_i @ (Wi+Wd) + b1 ;
//       c2P = x_j @ (Wj-Wd) in MFMA C-fragment order:
//         c2P[(j>>4)*2048 + (h>>4)*256 + (((j&15)>>2)*16 + (h&15))*4 + (j&3)]
//       wpack = Wab in per-lane bf16 MFMA B-fragment order (spread over blocks 0..63).
// ---------------------------------------------------------------------------
__global__ __launch_bounds__(256) void prep_kernel(
    const float* __restrict__ x, const float* __restrict__ W1,
    const float* __restrict__ b1,
    float* __restrict__ c1, float* __restrict__ c2P,
    unsigned short* __restrict__ wpack)
{
    __shared__ float xr[2][DD];
    const int t = threadIdx.x;
    const int i0 = blockIdx.x * 2;
    if (t < 2 * DD) xr[t >> 6][t & 63] = x[i0 * DD + t];
    __syncthreads();

    const int ii = t >> 7, h = t & 127;
    const int i = i0 + ii;
    float a1 = 0.f, a2 = 0.f;
    #pragma unroll 16
    for (int k = 0; k < DD; k++) {
        float wi = W1[k * HH + h];
        float wj = W1[(DD + k) * HH + h];
        float wd = W1[(2 * DD + k) * HH + h];
        float xv = xr[ii][k];
        a1 = fmaf(xv, wi + wd, a1);
        a2 = fmaf(xv, wj - wd, a2);
    }
    c1[i * HH + h] = a1 + b1[h];
    const int jl = i & 15;
    c2P[(i >> 4) * 2048 + (h >> 4) * 256 + (((jl >> 2) << 4) | (h & 15)) * 4 + (jl & 3)] = a2;

    if (blockIdx.x < 64) {
        // one element per thread: wpack[((t8*2+s)*64+lane)*8+jj] = bf16(Wab[s*32+(lane>>4)*8+jj][t8*16+(lane&15)])
        int f = blockIdx.x * 256 + t;
        int jj = f & 7, l = (f >> 3) & 63, u = f >> 9;
        int s = u & 1, t8 = u >> 1;
        int k = s * 32 + ((l >> 4) << 3) + jj;
        int hh = t8 * 16 + (l & 15);
        wpack[f] = f2bf(W1[(3 * DD + k) * HH + hh]);
    }
}

// ---------------------------------------------------------------------------
// Pair kernel: Sp[jq][i][h] = sum_{j in quarter jq} relu(|x_i-x_j|@Wab + c1[i]+c2[j])
// Block = 4 waves; each wave owns 2 consecutive i (block = 8 i), one j-quarter.
// j-quarter = 8 supertiles of 32 j. xs is XOR-swizzled (chunk c of row j stored
// at position c^(j&7)) so the MFMA A-operand b128 reads are bank-conflict-free.
// c2 arrives pre-permuted in C-fragment order (sequential per-lane b128).
// ---------------------------------------------------------------------------
__global__ __launch_bounds__(256, 2) void pair_kernel(
    const float* __restrict__ x, const float* __restrict__ c1,
    const float* __restrict__ c2P, const unsigned short* __restrict__ wpack,
    float* __restrict__ Sp)
{
    __shared__ __align__(16) float xs[2][2048];   // 2 x 8 KB (32 j x 64 k, swizzled)
    __shared__ __align__(16) float c2s[2][4096];  // 2 x 16 KB (2 subtile fragments)

    const int t = threadIdx.x;
    const int wave = t >> 6;
    const int l = t & 63;
    const int quad = l >> 4, lm = l & 15;
    const int ig = blockIdx.x >> 2;
    const int jq = blockIdx.x & 3;
    const int i0 = ig * 8 + wave * 2;
    const int j0base = jq * 256;

    // ---- stage supertile 0 (async) ----
    {
        const int j0 = j0base;
        #pragma unroll
        for (int p = 0; p < 2; p++) {
            int j = p * 16 + wave * 4 + quad;
            int c = lm ^ (j & 7);
            async_cp16(x + (j0 + j) * DD + c * 4, &xs[0][0] + p * 1024 + wave * 256);
        }
        const float* cg = c2P + (j0 >> 4) * 2048;
        #pragma unroll
        for (int p = 0; p < 4; p++)
            async_cp16(cg + (p * 256 + wave * 64 + l) * 4, &c2s[0][0] + p * 1024 + wave * 256);
    }

    // ---- wave-private register data (overlaps staging) ----
    float xi[2][16];
    #pragma unroll
    for (int ii = 0; ii < 2; ii++) {
        const float* xg = x + (i0 + ii) * DD + quad * 8;
        *(float4*)(xi[ii])      = *(const float4*)(xg);
        *(float4*)(xi[ii] + 4)  = *(const float4*)(xg + 4);
        *(float4*)(xi[ii] + 8)  = *(const float4*)(xg + 32);
        *(float4*)(xi[ii] + 12) = *(const float4*)(xg + 36);
    }
    float c1r[2][8];
    #pragma unroll
    for (int ii = 0; ii < 2; ii++)
        #pragma unroll
        for (int t8 = 0; t8 < 8; t8++)
            c1r[ii][t8] = c1[(i0 + ii) * HH + t8 * 16 + lm];
    bf16x8 wf[16];
    #pragma unroll
    for (int u = 0; u < 16; u++)
        wf[u] = *(const bf16x8*)(wpack + (u * 64 + l) * 8);

    float S[2][8];
    #pragma unroll
    for (int ii = 0; ii < 2; ii++)
        #pragma unroll
        for (int t8 = 0; t8 < 8; t8++) S[ii][t8] = 0.f;

    const int sw = lm & 7;

    for (int tile = 0; tile < 8; ++tile) {
        const int cur = tile & 1;
        __syncthreads();   // staged data for 'tile' landed; other buffer free

        if (tile < 7) {    // prefetch next supertile (async)
            const int j0 = j0base + (tile + 1) * 32;
            const int nb = cur ^ 1;
            #pragma unroll
            for (int p = 0; p < 2; p++) {
                int j = p * 16 + wave * 4 + quad;
                int c = lm ^ (j & 7);
                async_cp16(x + (j0 + j) * DD + c * 4, &xs[nb][0] + p * 1024 + wave * 256);
            }
            const float* cg = c2P + (j0 >> 4) * 2048;
            #pragma unroll
            for (int p = 0; p < 4; p++)
                async_cp16(cg + (p * 256 + wave * 64 + l) * 4, &c2s[nb][0] + p * 1024 + wave * 256);
        }

        #pragma unroll
        for (int st = 0; st < 2; st++) {
            // A-source: row r = st*16+lm, chunks quad*2,+1,+8,+9 (swizzled by r&7==lm&7)
            const float* xb = &xs[cur][0] + (st * 16 + lm) * 16 * 4;
            float4 a0 = *(const float4*)(xb + ((quad * 2)     ^ sw) * 4);
            float4 a1 = *(const float4*)(xb + ((quad * 2 + 1) ^ sw) * 4);
            float4 a2 = *(const float4*)(xb + ((quad * 2 + 8) ^ sw) * 4);
            float4 a3 = *(const float4*)(xb + ((quad * 2 + 9) ^ sw) * 4);

            floatx4 acc[2][8];
            #pragma unroll
            for (int ii = 0; ii < 2; ii++)
                #pragma unroll
                for (int t8 = 0; t8 < 8; t8++) {
                    acc[ii][t8][0] = c1r[ii][t8]; acc[ii][t8][1] = c1r[ii][t8];
                    acc[ii][t8][2] = c1r[ii][t8]; acc[ii][t8][3] = c1r[ii][t8];
                }

            #pragma unroll
            for (int ii = 0; ii < 2; ii++) {
                bf16x8 af0, af1;
                af0[0] = (__bf16)fabsf(xi[ii][0] - a0.x);  af0[1] = (__bf16)fabsf(xi[ii][1] - a0.y);
                af0[2] = (__bf16)fabsf(xi[ii][2] - a0.z);  af0[3] = (__bf16)fabsf(xi[ii][3] - a0.w);
                af0[4] = (__bf16)fabsf(xi[ii][4] - a1.x);  af0[5] = (__bf16)fabsf(xi[ii][5] - a1.y);
                af0[6] = (__bf16)fabsf(xi[ii][6] - a1.z);  af0[7] = (__bf16)fabsf(xi[ii][7] - a1.w);
                af1[0] = (__bf16)fabsf(xi[ii][8] - a2.x);  af1[1] = (__bf16)fabsf(xi[ii][9] - a2.y);
                af1[2] = (__bf16)fabsf(xi[ii][10] - a2.z); af1[3] = (__bf16)fabsf(xi[ii][11] - a2.w);
                af1[4] = (__bf16)fabsf(xi[ii][12] - a3.x); af1[5] = (__bf16)fabsf(xi[ii][13] - a3.y);
                af1[6] = (__bf16)fabsf(xi[ii][14] - a3.z); af1[7] = (__bf16)fabsf(xi[ii][15] - a3.w);
                #pragma unroll
                for (int t8 = 0; t8 < 8; t8++) {
                    acc[ii][t8] = __builtin_amdgcn_mfma_f32_16x16x32_bf16(af0, wf[t8 * 2 + 0], acc[ii][t8], 0, 0, 0);
                    acc[ii][t8] = __builtin_amdgcn_mfma_f32_16x16x32_bf16(af1, wf[t8 * 2 + 1], acc[ii][t8], 0, 0, 0);
                }
            }

            // epilogue: +c2 (fragment-ordered sequential b128), relu, sum over j
            #pragma unroll
            for (int t8 = 0; t8 < 8; t8++) {
                float4 c2v = *(const float4*)(&c2s[cur][st * 2048 + t8 * 256 + l * 4]);
                #pragma unroll
                for (int ii = 0; ii < 2; ii++) {
                    S[ii][t8] += fmaxf(acc[ii][t8][0] + c2v.x, 0.f);
                    S[ii][t8] += fmaxf(acc[ii][t8][1] + c2v.y, 0.f);
                    S[ii][t8] += fmaxf(acc[ii][t8][2] + c2v.z, 0.f);
                    S[ii][t8] += fmaxf(acc[ii][t8][3] + c2v.w, 0.f);
                }
            }
        }
    }

    // reduce across the 4 quads (same h = lm+16*t8, different j-rows)
    #pragma unroll
    for (int ii = 0; ii < 2; ii++)
        #pragma unroll
        for (int t8 = 0; t8 < 8; t8++) {
            S[ii][t8] += __shfl_xor(S[ii][t8], 16, 64);
            S[ii][t8] += __shfl_xor(S[ii][t8], 32, 64);
        }
    if (quad == 0) {
        #pragma unroll
        for (int ii = 0; ii < 2; ii++)
            #pragma unroll
            for (int t8 = 0; t8 < 8; t8++)
                Sp[(jq * BB + i0 + ii) * HH + t8 * 16 + lm] = S[ii][t8];
    }
}

// ---------------------------------------------------------------------------
// Finish (head+tail merged): per row i
//   m = (b2 + (mean_j S) @ W2)/tau ; h = relu(m@Wa+ba); y = h + x@Wr + br;
//   out = LayerNorm(y)*gamma+beta.  Block = 2 i x 128 h.
// ---------------------------------------------------------------------------
__global__ __launch_bounds__(256) void finish_kernel(
    const float* __restrict__ Sp, const float* __restrict__ W2,
    const float* __restrict__ b2, const float* __restrict__ x,
    const float* __restrict__ Wt, const float* __restrict__ bt,
    const float* __restrict__ Wa, const float* __restrict__ ba,
    const float* __restrict__ Wr, const float* __restrict__ br,
    const float* __restrict__ gamma, const float* __restrict__ beta,
    float* __restrict__ out)
{
    __shared__ float Srow[2][HH];
    __shared__ float mrow[2][HH];
    __shared__ float xrow[2][DD];
    __shared__ float taus[2];
    __shared__ float red1[2][2];
    __shared__ float red2[2][2];
    const int t = threadIdx.x;
    const int ii = t >> 7, h = t & 127;
    const int i = blockIdx.x * 2 + ii;

    float s = 0.f;
    #pragma unroll
    for (int q = 0; q < 4; q++) s += Sp[(q * BB + i) * HH + h];
    Srow[ii][h] = s * (1.0f / (float)BB);
    if (h < 64) xrow[ii][h] = x[i * DD + h];

    if ((t & 127) < 64) {
        int lane = t & 63;
        float p = x[i * DD + lane] * Wt[lane];
        #pragma unroll
        for (int off = 32; off; off >>= 1) p += __shfl_down(p, off, 64);
        if (lane == 0) {
            float z = p + bt[0];
            float sp = (z > 20.f) ? z : log1pf(expf(z));
            taus[ii] = fmaxf(sp, 0.01f) + 1.0f;
        }
    }
    __syncthreads();

    float acc = b2[h];
    #pragma unroll 8
    for (int k = 0; k < HH; k++) acc += Srow[ii][k] * W2[k * HH + h];
    float mv = acc / taus[ii];
    mrow[ii][h] = mv;
    __syncthreads();

    float acc2 = ba[h];
    #pragma unroll 8
    for (int k = 0; k < HH; k++) acc2 += mrow[ii][k] * Wa[k * HH + h];
    float y = fmaxf(acc2, 0.f) + br[h];
    #pragma unroll 8
    for (int d = 0; d < DD; d++) y += xrow[ii][d] * Wr[d * HH + h];

    const int wv = (t >> 6) & 1;
    const int lane = t & 63;
    float p = y;
    #pragma unroll
    for (int off = 32; off; off >>= 1) p += __shfl_down(p, off, 64);
    if (lane == 0) red1[ii][wv] = p;
    __syncthreads();
    float mu = (red1[ii][0] + red1[ii][1]) * (1.f / (float)HH);
    float dy = y - mu;
    float q = dy * dy;
    #pragma unroll
    for (int off = 32; off; off >>= 1) q += __shfl_down(q, off, 64);
    if (lane == 0) red2[ii][wv] = q;
    __syncthreads();
    float var = (red2[ii][0] + red2[ii][1]) * (1.f / (float)HH);
    out[i * HH + h] = dy * rsqrtf(var + 1e-5f) * gamma[h] + beta[h];
}

// ---------------------------------------------------------------------------
extern "C" void kernel_launch(void* const* d_in, const int* in_sizes, int n_in,
                              void* d_out, int out_size, void* d_ws, size_t ws_size,
                              hipStream_t stream)
{
    const float* x     = (const float*)d_in[0];
    const float* W1    = (const float*)d_in[1];
    const float* b1    = (const float*)d_in[2];
    const float* W2    = (const float*)d_in[3];
    const float* b2    = (const float*)d_in[4];
    const float* Wt    = (const float*)d_in[5];
    const float* bt    = (const float*)d_in[6];
    const float* Wa    = (const float*)d_in[7];
    const float* ba    = (const float*)d_in[8];
    const float* Wr    = (const float*)d_in[9];
    const float* br    = (const float*)d_in[10];
    const float* gamma = (const float*)d_in[11];
    const float* beta  = (const float*)d_in[12];
    float* out = (float*)d_out;

    char* ws = (char*)d_ws;
    float*          c1    = (float*)(ws);                         // 512 KB
    float*          c2P   = (float*)(ws + (512 << 10));           // 512 KB
    unsigned short* wpack = (unsigned short*)(ws + (1024 << 10)); // 32 KB
    float*          Sp    = (float*)(ws + (1056 << 10));          // 2 MB

    prep_kernel<<<512, 256, 0, stream>>>(x, W1, b1, c1, c2P, wpack);
    pair_kernel<<<512, 256, 0, stream>>>(x, c1, c2P, wpack, Sp);
    finish_kernel<<<BB / 2, 256, 0, stream>>>(Sp, W2, b2, x, Wt, bt,
                                              Wa, ba, Wr, br, gamma, beta, out);
}

// Round 4
// 141.485 us; speedup vs baseline: 1.7402x; 1.7402x over previous
//
#include <hip/hip_runtime.h>
#include <hip/hip_bf16.h>
#include <math.h>

#define BB 1024
#define DD 64
#define HH 128

typedef __bf16 bf16x8 __attribute__((ext_vector_type(8)));
typedef float floatx4 __attribute__((ext_vector_type(4)));

__device__ __forceinline__ unsigned short f2bf(float v) {
    union { float f; unsigned u; } a; a.f = v;
    unsigned r = a.u + 0x7fffu + ((a.u >> 16) & 1u);
    return (unsigned short)(r >> 16);
}

// async global -> LDS, 16B per lane. lds base must be wave-uniform; HW adds lane*16.
__device__ __forceinline__ void async_cp16(const float* g, float* lds_wave_base) {
    __builtin_amdgcn_global_load_lds(
        (const __attribute__((address_space(1))) unsigned int*)g,
        (__attribute__((address_space(3))) unsigned int*)lds_wave_base,
        16, 0, 0);
}

// ---------------------------------------------------------------------------
// Prep: c1[i,h] = x_i @ (Wi+Wd) + b1 ;
//       c2P = x_j @ (Wj-Wd) in MFMA C-fragment order:
//         c2P[(j>>4)*2048 + (h>>4)*256 + (((j&15)>>2)*16 + (h&15))*4 + (j&3)]
//       wpack = Wab in per-lane bf16 MFMA B-fragment order (blocks 0..63).
// ---------------------------------------------------------------------------
__global__ __launch_bounds__(256) void prep_kernel(
    const float* __restrict__ x, const float* __restrict__ W1,
    const float* __restrict__ b1,
    float* __restrict__ c1, float* __restrict__ c2P,
    unsigned short* __restrict__ wpack)
{
    __shared__ float xr[2][DD];
    const int t = threadIdx.x;
    const int i0 = blockIdx.x * 2;
    if (t < 2 * DD) xr[t >> 6][t & 63] = x[i0 * DD + t];
    __syncthreads();

    const int ii = t >> 7, h = t & 127;
    const int i = i0 + ii;
    float a1 = 0.f, a2 = 0.f;
    #pragma unroll 16
    for (int k = 0; k < DD; k++) {
        float wi = W1[k * HH + h];
        float wj = W1[(DD + k) * HH + h];
        float wd = W1[(2 * DD + k) * HH + h];
        float xv = xr[ii][k];
        a1 = fmaf(xv, wi + wd, a1);
        a2 = fmaf(xv, wj - wd, a2);
    }
    c1[i * HH + h] = a1 + b1[h];
    const int jl = i & 15;
    c2P[(i >> 4) * 2048 + (h >> 4) * 256 + (((jl >> 2) << 4) | (h & 15)) * 4 + (jl & 3)] = a2;

    if (blockIdx.x < 64) {
        // wpack[((t8*2+s)*64+lane)*8+jj] = bf16(Wab[s*32+(lane>>4)*8+jj][t8*16+(lane&15)])
        int f = blockIdx.x * 256 + t;
        int jj = f & 7, l = (f >> 3) & 63, u = f >> 9;
        int s = u & 1, t8 = u >> 1;
        int k = s * 32 + ((l >> 4) << 3) + jj;
        int hh = t8 * 16 + (l & 15);
        wpack[f] = f2bf(W1[(3 * DD + k) * HH + hh]);
    }
}

// ---------------------------------------------------------------------------
// Pair kernel: Sp[jq][i][h] = sum_{j in quarter jq} relu(|x_i-x_j|@Wab + c1[i]+c2[j])
// Block = 4 waves = 4 consecutive i, one j-quarter (256 j = 16 tiles of 16).
// xs is XOR-swizzled (16B chunk c of row j stored at c^(j&7)) => the 4
// ds_read_b128 A-operand reads hit all 32 banks uniformly (conflict-free).
// c2 is NOT staged in LDS: fragment-ordered c2P makes lane l's float4 a
// perfectly coalesced global dwordx4 (L2-resident), folded into acc init.
// ---------------------------------------------------------------------------
__global__ __launch_bounds__(256) void pair_kernel(
    const float* __restrict__ x, const float* __restrict__ c1,
    const float* __restrict__ c2P, const unsigned short* __restrict__ wpack,
    float* __restrict__ Sp)
{
    __shared__ __align__(16) float xs[2][1024];   // 2 x 4 KB (16 j x 64 k, swizzled)

    const int t = threadIdx.x;
    const int wave = t >> 6;
    const int l = t & 63;
    const int quad = l >> 4, lm = l & 15;
    const int ig = blockIdx.x >> 2;
    const int jq = blockIdx.x & 3;
    const int i = ig * 4 + wave;
    const int j0base = jq * 256;
    const int sw = lm & 7;

    // stage tile 0 (async): thread t -> row j=t>>4, chunk pos t&15,
    // source chunk (t&15)^(j&7)  (swizzled at zero cost on the write side)
    async_cp16(x + (j0base + (t >> 4)) * DD + (((t & 15) ^ ((t >> 4) & 7)) << 2),
               &xs[0][0] + wave * 256);

    // wave-private register data (overlaps staging)
    float xi[16];
    {
        const float* xg = x + i * DD + quad * 8;
        *(float4*)(xi)      = *(const float4*)(xg);
        *(float4*)(xi + 4)  = *(const float4*)(xg + 4);
        *(float4*)(xi + 8)  = *(const float4*)(xg + 32);
        *(float4*)(xi + 12) = *(const float4*)(xg + 36);
    }
    float c1r[8];
    #pragma unroll
    for (int t8 = 0; t8 < 8; t8++) c1r[t8] = c1[i * HH + t8 * 16 + lm];
    bf16x8 wf[16];
    #pragma unroll
    for (int u = 0; u < 16; u++)
        wf[u] = *(const bf16x8*)(wpack + (u * 64 + l) * 8);

    float S[8];
    #pragma unroll
    for (int t8 = 0; t8 < 8; t8++) S[t8] = 0.f;

    for (int tile = 0; tile < 16; ++tile) {
        const int cur = tile & 1;
        __syncthreads();   // staged data for 'tile' landed; other buffer free

        if (tile < 15) {   // prefetch next tile (async)
            const int jn = j0base + (tile + 1) * 16;
            async_cp16(x + (jn + (t >> 4)) * DD + (((t & 15) ^ ((t >> 4) & 7)) << 2),
                       &xs[cur ^ 1][0] + wave * 256);
        }

        // acc init = c2 (coalesced global dwordx4 from fragment-ordered c2P) + c1
        const float* cg = c2P + ((j0base + tile * 16) >> 4) * 2048;
        floatx4 acc[8];
        #pragma unroll
        for (int t8 = 0; t8 < 8; t8++) {
            float4 c2v = *(const float4*)(cg + t8 * 256 + l * 4);
            acc[t8][0] = c2v.x + c1r[t8];
            acc[t8][1] = c2v.y + c1r[t8];
            acc[t8][2] = c2v.z + c1r[t8];
            acc[t8][3] = c2v.w + c1r[t8];
        }

        // A fragment: row r=lm, chunks quad*2, +1, +8, +9, swizzled by sw=lm&7
        const float* xb = &xs[cur][lm * 64];
        float4 a0 = *(const float4*)(xb + (((quad * 2)     ^ sw) << 2));
        float4 a1 = *(const float4*)(xb + (((quad * 2 + 1) ^ sw) << 2));
        float4 a2 = *(const float4*)(xb + (((quad * 2 + 8) ^ sw) << 2));
        float4 a3 = *(const float4*)(xb + (((quad * 2 + 9) ^ sw) << 2));
        bf16x8 af0, af1;
        af0[0] = (__bf16)fabsf(xi[0] - a0.x);  af0[1] = (__bf16)fabsf(xi[1] - a0.y);
        af0[2] = (__bf16)fabsf(xi[2] - a0.z);  af0[3] = (__bf16)fabsf(xi[3] - a0.w);
        af0[4] = (__bf16)fabsf(xi[4] - a1.x);  af0[5] = (__bf16)fabsf(xi[5] - a1.y);
        af0[6] = (__bf16)fabsf(xi[6] - a1.z);  af0[7] = (__bf16)fabsf(xi[7] - a1.w);
        af1[0] = (__bf16)fabsf(xi[8] - a2.x);  af1[1] = (__bf16)fabsf(xi[9] - a2.y);
        af1[2] = (__bf16)fabsf(xi[10] - a2.z); af1[3] = (__bf16)fabsf(xi[11] - a2.w);
        af1[4] = (__bf16)fabsf(xi[12] - a3.x); af1[5] = (__bf16)fabsf(xi[13] - a3.y);
        af1[6] = (__bf16)fabsf(xi[14] - a3.z); af1[7] = (__bf16)fabsf(xi[15] - a3.w);

        #pragma unroll
        for (int t8 = 0; t8 < 8; t8++) {
            acc[t8] = __builtin_amdgcn_mfma_f32_16x16x32_bf16(af0, wf[t8 * 2 + 0], acc[t8], 0, 0, 0);
            acc[t8] = __builtin_amdgcn_mfma_f32_16x16x32_bf16(af1, wf[t8 * 2 + 1], acc[t8], 0, 0, 0);
        }
        #pragma unroll
        for (int t8 = 0; t8 < 8; t8++) {
            S[t8] += fmaxf(acc[t8][0], 0.f);
            S[t8] += fmaxf(acc[t8][1], 0.f);
            S[t8] += fmaxf(acc[t8][2], 0.f);
            S[t8] += fmaxf(acc[t8][3], 0.f);
        }
    }

    // reduce across the 4 quads (same h = lm+16*t8, different j-rows)
    #pragma unroll
    for (int t8 = 0; t8 < 8; t8++) {
        S[t8] += __shfl_xor(S[t8], 16, 64);
        S[t8] += __shfl_xor(S[t8], 32, 64);
    }
    if (quad == 0) {
        #pragma unroll
        for (int t8 = 0; t8 < 8; t8++)
            Sp[(jq * BB + i) * HH + t8 * 16 + lm] = S[t8];
    }
}

// ---------------------------------------------------------------------------
// Finish (head+tail merged): per row i
//   m = (b2 + (mean_j S) @ W2)/tau ; h = relu(m@Wa+ba); y = h + x@Wr + br;
//   out = LayerNorm(y)*gamma+beta.  Block = 2 i x 128 h.
// ---------------------------------------------------------------------------
__global__ __launch_bounds__(256) void finish_kernel(
    const float* __restrict__ Sp, const float* __restrict__ W2,
    const float* __restrict__ b2, const float* __restrict__ x,
    const float* __restrict__ Wt, const float* __restrict__ bt,
    const float* __restrict__ Wa, const float* __restrict__ ba,
    const float* __restrict__ Wr, const float* __restrict__ br,
    const float* __restrict__ gamma, const float* __restrict__ beta,
    float* __restrict__ out)
{
    __shared__ float Srow[2][HH];
    __shared__ float mrow[2][HH];
    __shared__ float xrow[2][DD];
    __shared__ float taus[2];
    __shared__ float red1[2][2];
    __shared__ float red2[2][2];
    const int t = threadIdx.x;
    const int ii = t >> 7, h = t & 127;
    const int i = blockIdx.x * 2 + ii;

    float s = 0.f;
    #pragma unroll
    for (int q = 0; q < 4; q++) s += Sp[(q * BB + i) * HH + h];
    Srow[ii][h] = s * (1.0f / (float)BB);
    if (h < 64) xrow[ii][h] = x[i * DD + h];

    if ((t & 127) < 64) {
        int lane = t & 63;
        float p = x[i * DD + lane] * Wt[lane];
        #pragma unroll
        for (int off = 32; off; off >>= 1) p += __shfl_down(p, off, 64);
        if (lane == 0) {
            float z = p + bt[0];
            float sp = (z > 20.f) ? z : log1pf(expf(z));
            taus[ii] = fmaxf(sp, 0.01f) + 1.0f;
        }
    }
    __syncthreads();

    float acc = b2[h];
    #pragma unroll 8
    for (int k = 0; k < HH; k++) acc += Srow[ii][k] * W2[k * HH + h];
    float mv = acc / taus[ii];
    mrow[ii][h] = mv;
    __syncthreads();

    float acc2 = ba[h];
    #pragma unroll 8
    for (int k = 0; k < HH; k++) acc2 += mrow[ii][k] * Wa[k * HH + h];
    float y = fmaxf(acc2, 0.f) + br[h];
    #pragma unroll 8
    for (int d = 0; d < DD; d++) y += xrow[ii][d] * Wr[d * HH + h];

    const int wv = (t >> 6) & 1;
    const int lane = t & 63;
    float p = y;
    #pragma unroll
    for (int off = 32; off; off >>= 1) p += __shfl_down(p, off, 64);
    if (lane == 0) red1[ii][wv] = p;
    __syncthreads();
    float mu = (red1[ii][0] + red1[ii][1]) * (1.f / (float)HH);
    float dy = y - mu;
    float q = dy * dy;
    #pragma unroll
    for (int off = 32; off; off >>= 1) q += __shfl_down(q, off, 64);
    if (lane == 0) red2[ii][wv] = q;
    __syncthreads();
    float var = (red2[ii][0] + red2[ii][1]) * (1.f / (float)HH);
    out[i * HH + h] = dy * rsqrtf(var + 1e-5f) * gamma[h] + beta[h];
}

// ---------------------------------------------------------------------------
extern "C" void kernel_launch(void* const* d_in, const int* in_sizes, int n_in,
                              void* d_out, int out_size, void* d_ws, size_t ws_size,
                              hipStream_t stream)
{
    const float* x     = (const float*)d_in[0];
    const float* W1    = (const float*)d_in[1];
    const float* b1    = (const float*)d_in[2];
    const float* W2    = (const float*)d_in[3];
    const float* b2    = (const float*)d_in[4];
    const float* Wt    = (const float*)d_in[5];
    const float* bt    = (const float*)d_in[6];
    const float* Wa    = (const float*)d_in[7];
    const float* ba    = (const float*)d_in[8];
    const float* Wr    = (const float*)d_in[9];
    const float* br    = (const float*)d_in[10];
    const float* gamma = (const float*)d_in[11];
    const float* beta  = (const float*)d_in[12];
    float* out = (float*)d_out;

    char* ws = (char*)d_ws;
    float*          c1    = (float*)(ws);                         // 512 KB
    float*          c2P   = (float*)(ws + (512 << 10));           // 512 KB
    unsigned short* wpack = (unsigned short*)(ws + (1024 << 10)); // 32 KB
    float*          Sp    = (float*)(ws + (1056 << 10));          // 2 MB

    prep_kernel<<<512, 256, 0, stream>>>(x, W1, b1, c1, c2P, wpack);
    pair_kernel<<<1024, 256, 0, stream>>>(x, c1, c2P, wpack, Sp);
    finish_kernel<<<BB / 2, 256, 0, stream>>>(Sp, W2, b2, x, Wt, bt,
                                              Wa, ba, Wr, br, gamma, beta, out);
}